// Round 1
// baseline (503.981 us; speedup 1.0000x reference)
//
#include <hip/hip_runtime.h>
#include <hip/hip_bf16.h>

// M=K=N=8192. x:[M,K] fp32, weight:[N,K] fp32.
// y[m] = 0.75 * dot(x[m,:], colsum(weight))  -> out is [M,1] fp32 (8192 floats)

#define M_DIM 8192
#define K_DIM 8192
#define N_DIM 8192

// ---------------- Kernel 1: column-sum of weight over rows ----------------
// weight is [N, K] row-major. wcs[k] = sum_n weight[n*K + k].
// grid: (K/1024 = 8 column-groups, N/64 = 128 row-chunks), block = 256 threads.
// Each thread owns 4 consecutive columns (one float4), loops 64 rows,
// then atomicAdds its 4 partial sums into wcs (zeroed beforehand).
__global__ __launch_bounds__(256) void colsum_kernel(
    const float* __restrict__ w, float* __restrict__ wcs) {
    constexpr int ROWS = 64;
    const int col4 = blockIdx.x * 256 + threadIdx.x;   // float4-column index
    const int row0 = blockIdx.y * ROWS;
    const int stride4 = K_DIM / 4;
    const float4* __restrict__ p =
        (const float4*)w + (size_t)row0 * stride4 + col4;

    float4 acc = make_float4(0.f, 0.f, 0.f, 0.f);
    #pragma unroll 8
    for (int r = 0; r < ROWS; ++r) {
        float4 v = p[(size_t)r * stride4];
        acc.x += v.x; acc.y += v.y; acc.z += v.z; acc.w += v.w;
    }
    float* out = wcs + col4 * 4;
    atomicAdd(out + 0, acc.x);
    atomicAdd(out + 1, acc.y);
    atomicAdd(out + 2, acc.z);
    atomicAdd(out + 3, acc.w);
}

// ---------------- Kernel 2: per-row dot with wcs ----------------
// One block (256 threads) per row of x. wcs is 32 KB -> lives in L2/L3.
__global__ __launch_bounds__(256) void rowdot_kernel(
    const float* __restrict__ x, const float* __restrict__ wcs,
    float* __restrict__ y) {
    const int m = blockIdx.x;
    const float4* __restrict__ x4 = (const float4*)(x + (size_t)m * K_DIM);
    const float4* __restrict__ w4 = (const float4*)wcs;

    float acc = 0.f;
    #pragma unroll 8
    for (int i = threadIdx.x; i < K_DIM / 4; i += 256) {
        float4 a = x4[i];
        float4 b = w4[i];
        acc += a.x * b.x + a.y * b.y + a.z * b.z + a.w * b.w;
    }
    // wave-64 shuffle reduction
    #pragma unroll
    for (int off = 32; off > 0; off >>= 1)
        acc += __shfl_down(acc, off, 64);

    __shared__ float sacc[4];
    const int lane = threadIdx.x & 63;
    const int wave = threadIdx.x >> 6;
    if (lane == 0) sacc[wave] = acc;
    __syncthreads();
    if (threadIdx.x == 0) {
        y[m] = 0.75f * (sacc[0] + sacc[1] + sacc[2] + sacc[3]);
    }
}

extern "C" void kernel_launch(void* const* d_in, const int* in_sizes, int n_in,
                              void* d_out, int out_size, void* d_ws, size_t ws_size,
                              hipStream_t stream) {
    const float* x = (const float*)d_in[0];   // [M, K]
    const float* w = (const float*)d_in[1];   // [N, K]
    float* y = (float*)d_out;                 // [M] (== [M,1] flat)
    float* wcs = (float*)d_ws;                // [K] scratch

    // ws is poisoned 0xAA each call -> zero the accumulator (capture-safe).
    hipMemsetAsync(wcs, 0, K_DIM * sizeof(float), stream);

    dim3 g1(K_DIM / 1024, N_DIM / 64);        // 8 x 128 = 1024 blocks
    colsum_kernel<<<g1, 256, 0, stream>>>(w, wcs);

    rowdot_kernel<<<M_DIM, 256, 0, stream>>>(x, wcs, y);
}